// Round 6
// baseline (550.538 us; speedup 1.0000x reference)
//
#include <hip/hip_runtime.h>

// B=1024, S=200, D=64, C=256
// out[0] cluster_emb [B,C,D] f32, out[1] cluster_mask [B,C,S] f32
//
// ATTRIBUTION ROUND: single fused kernel, body repeated 4x (idempotent —
// writes identical values each pass). Purpose: push my dispatch above the
// ~180us harness poison fills so rocprof's top-5 shows MY dur_us/hbm_gbps.
// Per-pass time = dispatch_dur / 4 (277MB store set >> 32MB L2, so every
// pass pays full HBM write cost).
#define NB 1024
#define NS 200
#define ND 64
#define NC 256
#define NPASS 4

typedef float v4f __attribute__((ext_vector_type(4)));

__global__ __launch_bounds__(256) void s3rec_fused_x4(
    const float* __restrict__ x,       // [B,S,D]
    const int*   __restrict__ labels,  // [B,S]
    const int*   __restrict__ amask,   // [B,S]
    float* __restrict__ out_emb,       // [B,C,D]
    float* __restrict__ out_mask)      // [B,C,S]
{
    __shared__ __align__(16) float s_emb[NC * ND];   // 65536 B
    __shared__ __align__(16) int   s_lab[NS];
    __shared__ float s_inv[NC];

    const int b = blockIdx.x;
    const int t = threadIdx.x;
    const int lane = t & 63;
    const int w    = t >> 6;
    const float* xb = x + (size_t)b * NS * ND;
    v4f* om4 = reinterpret_cast<v4f*>(out_mask + (size_t)b * (NC * NS));
    v4f* oe4 = reinterpret_cast<v4f*>(out_emb  + (size_t)b * (NC * ND));
    v4f* se4 = reinterpret_cast<v4f*>(s_emb);
    const int4* lab4 = reinterpret_cast<const int4*>(s_lab);

    for (int pass = 0; pass < NPASS; ++pass) {
        // --- stage labels (packed with mask) + zero accumulator ---
        for (int i = t; i < NS; i += 256) {
            const int l = labels[b * NS + i];
            const int m = amask [b * NS + i];
            s_lab[i] = (m != 0) ? l : -1;
        }
        for (int i = t; i < (NC * ND) / 4; i += 256) {
            v4f z = {0.0f, 0.0f, 0.0f, 0.0f};
            se4[i] = z;
        }
        __syncthreads();

        // --- mask writes: 12800 v4f per batch, coalesced ---
        for (int i4 = t; i4 < (NC * NS) / 4; i4 += 256) {
            const int c  = i4 / 50;            // magic-mul
            const int s4 = i4 - c * 50;
            const int4 L = lab4[s4];
            v4f v;
            v.x = (L.x == c) ? 1.0f : 0.0f;
            v.y = (L.y == c) ? 1.0f : 0.0f;
            v.z = (L.z == c) ? 1.0f : 0.0f;
            v.w = (L.w == c) ? 1.0f : 0.0f;
            om4[i4] = v;
        }

        // --- emb accumulate: wave w takes s = w, w+4, ...; lane = d ---
        for (int s = w; s < NS; s += 4) {
            const int c = s_lab[s];
            if (c >= 0) {
                atomicAdd(&s_emb[c * ND + lane], xb[s * ND + lane]);
            }
        }

        // --- counts: thread t owns cluster t ---
        int cnt = 0;
        #pragma unroll 10
        for (int s4 = 0; s4 < NS / 4; ++s4) {
            const int4 L = lab4[s4];
            cnt += (L.x == t) + (L.y == t) + (L.z == t) + (L.w == t);
        }
        s_inv[t] = (cnt > 0) ? (1.0f / (float)cnt) : 0.0f;
        __syncthreads();

        // --- scaled emb store ---
        for (int i4 = t; i4 < (NC * ND) / 4; i4 += 256) {
            const float inv = s_inv[i4 >> 4];
            v4f v = se4[i4] * inv;
            oe4[i4] = v;
        }
        __syncthreads();   // protect s_emb/s_lab before next pass re-inits
    }
}

extern "C" void kernel_launch(void* const* d_in, const int* in_sizes, int n_in,
                              void* d_out, int out_size, void* d_ws, size_t ws_size,
                              hipStream_t stream) {
    const float* x      = (const float*)d_in[0];  // [B,S,D] f32
    const int*   labels = (const int*)  d_in[1];  // [B,S]   i32
    const int*   amask  = (const int*)  d_in[2];  // [B,S]   i32

    float* out_emb  = (float*)d_out;                   // [B,C,D]
    float* out_mask = out_emb + (size_t)NB * NC * ND;  // [B,C,S]

    s3rec_fused_x4<<<dim3(NB), dim3(256), 0, stream>>>(
        x, labels, amask, out_emb, out_mask);
}

// Round 7
// 473.364 us; speedup vs baseline: 1.1630x; 1.1630x over previous
//
#include <hip/hip_runtime.h>

// B=1024, S=200, D=64, C=256
// out[0] cluster_emb [B,C,D] f32, out[1] cluster_mask [B,C,S] f32
//
// MEASUREMENT MODE: NPASS=4 (idempotent) so this dispatch lands in rocprof
// top-5 with its own counters. Per-pass time = dispatch_dur / 4.
//
// R7 change vs R6: x-loads are hoisted out of the divergent atomic loop into
// 13 unconditional dwordx4 loads issued up front; mask stores + count loop
// execute in the load-latency shadow; predicated LDS atomics consume the
// registers afterwards. (R6: load inside divergent branch -> per-iter
// vmcnt(0) stall, ~50 serial latencies per wave.)
#define NB 1024
#define NS 200
#define ND 64
#define NC 256
#define NPASS 4

typedef float v4f __attribute__((ext_vector_type(4)));

__global__ __launch_bounds__(256) void s3rec_fused_x4(
    const float* __restrict__ x,       // [B,S,D]
    const int*   __restrict__ labels,  // [B,S]
    const int*   __restrict__ amask,   // [B,S]
    float* __restrict__ out_emb,       // [B,C,D]
    float* __restrict__ out_mask)      // [B,C,S]
{
    __shared__ __align__(16) float s_emb[NC * ND];   // 65536 B
    __shared__ __align__(16) int   s_lab[NS];
    __shared__ float s_inv[NC];

    const int b = blockIdx.x;
    const int t = threadIdx.x;
    const int lane = t & 63;
    const int w    = t >> 6;          // wave 0..3, owns s in [50w, 50w+50)
    const int r16  = lane >> 4;       // row-within-group 0..3
    const int d4   = lane & 15;       // dim quad 0..15 -> dims [4*d4, 4*d4+4)

    const v4f* xb4 = reinterpret_cast<const v4f*>(x + (size_t)b * NS * ND);
    v4f* om4 = reinterpret_cast<v4f*>(out_mask + (size_t)b * (NC * NS));
    v4f* oe4 = reinterpret_cast<v4f*>(out_emb  + (size_t)b * (NC * ND));
    v4f* se4 = reinterpret_cast<v4f*>(s_emb);
    const int4* lab4 = reinterpret_cast<const int4*>(s_lab);

    for (int pass = 0; pass < NPASS; ++pass) {
        // --- stage labels + zero accumulator ---
        for (int i = t; i < NS; i += 256) {
            const int l = labels[b * NS + i];
            const int m = amask [b * NS + i];
            s_lab[i] = (m != 0) ? l : -1;
        }
        for (int i = t; i < (NC * ND) / 4; i += 256) {
            v4f z = {0.0f, 0.0f, 0.0f, 0.0f};
            se4[i] = z;
        }
        __syncthreads();

        // --- (1) issue all x loads up front: 13 independent dwordx4/lane ---
        // Wave covers 4 s-rows per iter (16 lanes x 4 dims each).
        v4f xv[13];
        int sidx[13];
        #pragma unroll
        for (int it = 0; it < 13; ++it) {
            const int so = 4 * it + r16;             // 0..51
            const int s  = 50 * w + ((so < 50) ? so : 0);  // clamp (dup load ok)
            sidx[it] = (so < 50) ? s : -1;
            xv[it] = xb4[s * (ND / 4) + d4];
        }

        // --- (2) mask stores: run in the load-latency shadow ---
        for (int i4 = t; i4 < (NC * NS) / 4; i4 += 256) {
            const int c  = i4 / 50;                  // magic-mul
            const int s4 = i4 - c * 50;
            const int4 L = lab4[s4];
            v4f v;
            v.x = (L.x == c) ? 1.0f : 0.0f;
            v.y = (L.y == c) ? 1.0f : 0.0f;
            v.z = (L.z == c) ? 1.0f : 0.0f;
            v.w = (L.w == c) ? 1.0f : 0.0f;
            om4[i4] = v;
        }

        // --- (3) counts (LDS-only, also in the shadow): thread t = cluster t
        int cnt = 0;
        #pragma unroll 10
        for (int s4 = 0; s4 < NS / 4; ++s4) {
            const int4 L = lab4[s4];
            cnt += (L.x == t) + (L.y == t) + (L.z == t) + (L.w == t);
        }
        s_inv[t] = (cnt > 0) ? (1.0f / (float)cnt) : 0.0f;

        // --- (4) predicated LDS atomics consume the registers ---
        #pragma unroll
        for (int it = 0; it < 13; ++it) {
            const int s = sidx[it];
            if (s >= 0) {
                const int c = s_lab[s];
                if (c >= 0) {
                    float* dst = &s_emb[c * ND + 4 * d4];
                    atomicAdd(dst + 0, xv[it].x);
                    atomicAdd(dst + 1, xv[it].y);
                    atomicAdd(dst + 2, xv[it].z);
                    atomicAdd(dst + 3, xv[it].w);
                }
            }
        }
        __syncthreads();

        // --- scaled emb store ---
        for (int i4 = t; i4 < (NC * ND) / 4; i4 += 256) {
            const float inv = s_inv[i4 >> 4];
            v4f v = se4[i4] * inv;
            oe4[i4] = v;
        }
        __syncthreads();   // protect s_emb/s_lab before next pass
    }
}

extern "C" void kernel_launch(void* const* d_in, const int* in_sizes, int n_in,
                              void* d_out, int out_size, void* d_ws, size_t ws_size,
                              hipStream_t stream) {
    const float* x      = (const float*)d_in[0];  // [B,S,D] f32
    const int*   labels = (const int*)  d_in[1];  // [B,S]   i32
    const int*   amask  = (const int*)  d_in[2];  // [B,S]   i32

    float* out_emb  = (float*)d_out;                   // [B,C,D]
    float* out_mask = out_emb + (size_t)NB * NC * ND;  // [B,C,S]

    s3rec_fused_x4<<<dim3(NB), dim3(256), 0, stream>>>(
        x, labels, amask, out_emb, out_mask);
}